// Round 6
// baseline (204.253 us; speedup 1.0000x reference)
//
#include <hip/hip_runtime.h>

#define NB 16
#define NCIN 256
#define NL 2048
#define NHID 512
#define NM 512
#define NLP 1024

typedef short bf16x8 __attribute__((ext_vector_type(8)));
typedef unsigned short u16x8 __attribute__((ext_vector_type(8)));
typedef float f32x4 __attribute__((ext_vector_type(4)));
typedef __attribute__((address_space(1))) const unsigned int gas_u32;
typedef __attribute__((address_space(3))) unsigned int las_u32;

__device__ __forceinline__ unsigned short f2bf(float f) {
    unsigned int u = __builtin_bit_cast(unsigned int, f);
    return (unsigned short)((u + 0x7FFFu + ((u >> 16) & 1u)) >> 16);
}
__device__ __forceinline__ float bf2f(unsigned short u) {
    return __builtin_bit_cast(float, ((unsigned int)u) << 16);
}

// ================ k_front: conv1x1+bias+relu+pool direct from x (bb<512),
//                  plus P cast/transpose (512..639) and wT transpose (640..895)
__global__ __launch_bounds__(512) void k_front(
    const float* __restrict__ x, const float* __restrict__ w1,
    const float* __restrict__ b1, const float* __restrict__ P,
    const float* __restrict__ wT, unsigned short* __restrict__ hb,
    unsigned short* __restrict__ Pb, unsigned short* __restrict__ Ptb,
    unsigned short* __restrict__ wTt)
{
    __shared__ __align__(16) unsigned short smem[66560];  // 133,120 B
    const int bb = blockIdx.x;
    const int t = threadIdx.x;

    if (bb >= 512) {
        if (bb < 640) {   // P -> Pb (cast) and Ptb (transpose), 64x64 tiles
            unsigned short (*tbuf)[65] = (unsigned short (*)[65])smem;
            const int pb = bb - 512;
            const int mt = pb >> 4, lt = pb & 15;
            for (int i = t; i < 4096; i += 512) {
                const int r = i >> 6, c = i & 63;
                const unsigned short v = f2bf(P[(size_t)(mt * 64 + r) * 1024 + lt * 64 + c]);
                Pb[(size_t)(mt * 64 + r) * 1024 + lt * 64 + c] = v;
                tbuf[c][r] = v;
            }
            __syncthreads();
            for (int i = t; i < 4096; i += 512) {
                const int r = i >> 6, c = i & 63;
                Ptb[(size_t)(lt * 64 + r) * 512 + mt * 64 + c] = tbuf[r][c];
            }
        } else {          // wT -> wTt [g][(o,kk)][i]
            const int t5 = (bb - 640) * 512 + t;   // < 131072
            const int g = t5 >> 16, ok = (t5 >> 8) & 255, i = t5 & 255;
            wTt[t5] = f2bf(wT[(size_t)(g * 256 + i) * 256 + ok]);
        }
        return;
    }

    // ---- conv block: rows r0..r0+127 over (b,l), cols = 256 o of group g
    const int g  = bb & 1;
    const int rt = bb >> 1;
    const int r0 = rt * 128;
    const int b  = r0 >> 11, l0 = r0 & 2047;

    unsigned short* T   = smem;           // [128][136] bf16 (ch, l)
    unsigned short* Asl = smem + 17408;   // [128][128] bf16 (l, ch)
    unsigned short* Bsl = smem + 33792;   // [256][128] bf16 (o, ch)
    unsigned short* epi = smem;           // [256][72]  (reused after MFMA)

    // load x fp32 -> T bf16 [ch][l]
    #pragma unroll
    for (int i3 = 0; i3 < 8; ++i3) {
        const int idx = i3 * 512 + t;
        const int ch = idx >> 5, f4 = idx & 31;
        const float4 v = *(const float4*)(x + ((size_t)(b * 256 + g * 128 + ch)) * 2048 + l0 + f4 * 4);
        ushort4 u;
        u.x = f2bf(v.x); u.y = f2bf(v.y); u.z = f2bf(v.z); u.w = f2bf(v.w);
        *(ushort4*)(T + ch * 136 + f4 * 4) = u;
    }
    // load w1 fp32 -> Bsl bf16 [o][ch]
    #pragma unroll
    for (int i5 = 0; i5 < 16; ++i5) {
        const int idx = i5 * 512 + t;
        const int o = idx >> 5, f4 = idx & 31;
        const float4 v = *(const float4*)(w1 + ((size_t)(g * 256 + o)) * 128 + f4 * 4);
        ushort4 u;
        u.x = f2bf(v.x); u.y = f2bf(v.y); u.z = f2bf(v.z); u.w = f2bf(v.w);
        *(ushort4*)(Bsl + o * 128 + f4 * 4) = u;
    }
    __syncthreads();
    // transpose T[ch][l] -> Asl[l][ch]
    #pragma unroll
    for (int i4 = 0; i4 < 4; ++i4) {
        const int idx = i4 * 512 + t;
        const int ch = idx & 127, lo = idx >> 7;
        const u16x8 v = *(const u16x8*)(T + ch * 136 + lo * 8);
        #pragma unroll
        for (int u2 = 0; u2 < 8; ++u2)
            Asl[(lo * 8 + u2) * 128 + ch] = v[u2];
    }
    __syncthreads();

    const int lane = t & 63, wave = t >> 6;
    const int wm = wave & 1, wn = wave >> 1;      // 2 x 4 waves, tile 64x64
    const int q = lane >> 4, lm = lane & 15;

    f32x4 acc[4][4];
    #pragma unroll
    for (int i = 0; i < 4; ++i)
        #pragma unroll
        for (int j = 0; j < 4; ++j)
            #pragma unroll
            for (int r = 0; r < 4; ++r) acc[i][j][r] = 0.f;

    #pragma unroll
    for (int kc = 0; kc < 4; ++kc) {   // K=128 = 4 x 32
        bf16x8 af[4], bf[4];
        #pragma unroll
        for (int i = 0; i < 4; ++i)
            af[i] = *(const bf16x8*)(Asl + (wm * 64 + i * 16 + lm) * 128 + kc * 32 + q * 8);
        #pragma unroll
        for (int j = 0; j < 4; ++j)
            bf[j] = *(const bf16x8*)(Bsl + (wn * 64 + j * 16 + lm) * 128 + kc * 32 + q * 8);
        #pragma unroll
        for (int i = 0; i < 4; ++i)
            #pragma unroll
            for (int j = 0; j < 4; ++j)
                acc[i][j] = __builtin_amdgcn_mfma_f32_16x16x32_bf16(af[i], bf[j], acc[i][j], 0, 0, 0);
    }
    __syncthreads();   // Asl/Bsl/T dead; epi reuses region

    // epilogue: pool adjacent l (reg pairs) + bias + relu -> epi[o][lp]
    #pragma unroll
    for (int j = 0; j < 4; ++j) {
        const int col = wn * 64 + j * 16 + lm;            // o local [0,256)
        const float bias = b1[g * 256 + col];
        #pragma unroll
        for (int i = 0; i < 4; ++i) {
            const float p0 = fmaxf(fmaxf(acc[i][j][0], acc[i][j][1]) + bias, 0.f);
            const float p1 = fmaxf(fmaxf(acc[i][j][2], acc[i][j][3]) + bias, 0.f);
            const int lp_loc = wm * 32 + i * 8 + q * 2;   // [0,64)
            ushort2 u; u.x = f2bf(p0); u.y = f2bf(p1);
            *(ushort2*)(epi + col * 72 + lp_loc) = u;
        }
    }
    __syncthreads();
    const int c_loc = t >> 1, half = t & 1;
    unsigned short* dst = hb + ((size_t)(b * 512 + g * 256 + c_loc)) * 1024 + (l0 >> 1) + half * 32;
    #pragma unroll
    for (int u = 0; u < 4; ++u)
        *(u16x8*)(dst + u * 8) = *(const u16x8*)(epi + c_loc * 72 + half * 32 + u * 8);
}

// ================ gemm_sc: Sb[8192,512] bf16 = hb . Pb^T   (512 thr, 8 waves)
__global__ __launch_bounds__(512, 2) void gemm_sc(
    const unsigned short* __restrict__ A, const unsigned short* __restrict__ B,
    unsigned short* __restrict__ Sb)
{
    const int nt = blockIdx.x & 3;
    const int rt = blockIdx.x >> 2;
    const int r0 = rt * 128, n0 = nt * 128;

    __shared__ unsigned short Asl[128 * 64];
    __shared__ unsigned short Bsl[128 * 64];

    const int t = threadIdx.x;
    const int lane = t & 63;
    const int wave = t >> 6;
    const int wm = wave & 1, wn = wave >> 1;
    const int q = lane >> 4, lm = lane & 15;

    f32x4 acc[4][2];
    #pragma unroll
    for (int i = 0; i < 4; ++i)
        #pragma unroll
        for (int j = 0; j < 2; ++j)
            #pragma unroll
            for (int r = 0; r < 4; ++r) acc[i][j][r] = 0.f;

    for (int k0 = 0; k0 < 1024; k0 += 64) {
        #pragma unroll
        for (int rd = 0; rd < 2; ++rd) {
            const int e = rd * 4096 + t * 8;
            const int row = e >> 6, col = e & 63;
            const unsigned short* ga = A + (size_t)(r0 + row) * 1024 + k0 + col;
            __builtin_amdgcn_global_load_lds((gas_u32*)ga, (las_u32*)(Asl + e), 16, 0, 0);
            const unsigned short* gb = B + (size_t)(n0 + row) * 1024 + k0 + col;
            __builtin_amdgcn_global_load_lds((gas_u32*)gb, (las_u32*)(Bsl + e), 16, 0, 0);
        }
        __syncthreads();
        #pragma unroll
        for (int kk = 0; kk < 2; ++kk) {
            bf16x8 af[4], bf[2];
            #pragma unroll
            for (int i = 0; i < 4; ++i)
                af[i] = *(const bf16x8*)(Asl + (wm * 64 + i * 16 + lm) * 64 + kk * 32 + q * 8);
            #pragma unroll
            for (int j = 0; j < 2; ++j)
                bf[j] = *(const bf16x8*)(Bsl + (wn * 32 + j * 16 + lm) * 64 + kk * 32 + q * 8);
            #pragma unroll
            for (int i = 0; i < 4; ++i)
                #pragma unroll
                for (int j = 0; j < 2; ++j)
                    acc[i][j] = __builtin_amdgcn_mfma_f32_16x16x32_bf16(af[i], bf[j], acc[i][j], 0, 0, 0);
        }
        __syncthreads();
    }

    #pragma unroll
    for (int i = 0; i < 4; ++i)
        #pragma unroll
        for (int j = 0; j < 2; ++j)
            #pragma unroll
            for (int r = 0; r < 4; ++r)
                Sb[(size_t)(r0 + wm * 64 + i * 16 + q * 4 + r) * 512
                   + n0 + wn * 32 + j * 16 + lm] = f2bf(acc[i][j][r]);
}

// ================ gemm_retr_sm: fused softmax + retrieval
// h2T[b,lp,c] bf16 = Ptb . softmax(Sb_rows)^T   (512 thr, 8 waves)
__global__ __launch_bounds__(512, 2) void gemm_retr_sm(
    const unsigned short* __restrict__ Ptb, const unsigned short* __restrict__ Sb,
    unsigned short* __restrict__ h2T)
{
    const int tl = blockIdx.x & 31;
    const int b  = blockIdx.x >> 5;
    const int nt = tl & 3;
    const int rt = tl >> 2;
    const int r0 = rt * 128, n0 = nt * 128;

    __shared__ unsigned short Asl[128 * 64];
    __shared__ unsigned short Bsl[128 * 64];
    __shared__ float Mrow[128];
    __shared__ float Inv[128];

    const int t = threadIdx.x;
    const int lane = t & 63;
    const int wave = t >> 6;
    const int wm = wave & 1, wn = wave >> 1;
    const int q = lane >> 4, lm = lane & 15;

    // ---- softmax pre-pass: per c-row max & 1/sum(exp). 4 threads/row, 128 m each.
    {
        const int row = t >> 2, part = t & 3;
        const unsigned short* srow = Sb + ((size_t)b * 512 + n0 + row) * 512 + part * 128;
        float mx = -3.0e38f;
        #pragma unroll
        for (int u = 0; u < 16; ++u) {
            const u16x8 v = *(const u16x8*)(srow + u * 8);
            #pragma unroll
            for (int j = 0; j < 8; ++j) mx = fmaxf(mx, bf2f(v[j]));
        }
        mx = fmaxf(mx, __shfl_xor(mx, 1));
        mx = fmaxf(mx, __shfl_xor(mx, 2));
        float sum = 0.f;
        #pragma unroll
        for (int u = 0; u < 16; ++u) {
            const u16x8 v = *(const u16x8*)(srow + u * 8);
            #pragma unroll
            for (int j = 0; j < 8; ++j) sum += __expf(bf2f(v[j]) - mx);
        }
        sum += __shfl_xor(sum, 1);
        sum += __shfl_xor(sum, 2);
        if (part == 0) { Mrow[row] = mx; Inv[row] = 1.f / sum; }
    }
    __syncthreads();

    f32x4 acc[4][2];
    #pragma unroll
    for (int i = 0; i < 4; ++i)
        #pragma unroll
        for (int j = 0; j < 2; ++j)
            #pragma unroll
            for (int r = 0; r < 4; ++r) acc[i][j][r] = 0.f;

    for (int k0 = 0; k0 < 512; k0 += 64) {
        #pragma unroll
        for (int rd = 0; rd < 2; ++rd) {
            const int e = rd * 4096 + t * 8;
            const int row = e >> 6, col = e & 63;
            // A: Ptb via async staging
            const unsigned short* ga = Ptb + (size_t)(r0 + row) * 512 + k0 + col;
            __builtin_amdgcn_global_load_lds((gas_u32*)ga, (las_u32*)(Asl + e), 16, 0, 0);
            // B: raw scores -> exp((s-m))*inv -> bf16 -> LDS
            const u16x8 sv = *(const u16x8*)(Sb + ((size_t)b * 512 + n0 + row) * 512 + k0 + col);
            const float m = Mrow[row], inv = Inv[row];
            u16x8 ov;
            #pragma unroll
            for (int j = 0; j < 8; ++j) ov[j] = f2bf(__expf(bf2f(sv[j]) - m) * inv);
            *(u16x8*)(Bsl + e) = ov;
        }
        __syncthreads();
        #pragma unroll
        for (int kk = 0; kk < 2; ++kk) {
            bf16x8 af[4], bf[2];
            #pragma unroll
            for (int i = 0; i < 4; ++i)
                af[i] = *(const bf16x8*)(Asl + (wm * 64 + i * 16 + lm) * 64 + kk * 32 + q * 8);
            #pragma unroll
            for (int j = 0; j < 2; ++j)
                bf[j] = *(const bf16x8*)(Bsl + (wn * 32 + j * 16 + lm) * 64 + kk * 32 + q * 8);
            #pragma unroll
            for (int i = 0; i < 4; ++i)
                #pragma unroll
                for (int j = 0; j < 2; ++j)
                    acc[i][j] = __builtin_amdgcn_mfma_f32_16x16x32_bf16(af[i], bf[j], acc[i][j], 0, 0, 0);
        }
        __syncthreads();
    }

    #pragma unroll
    for (int i = 0; i < 4; ++i)
        #pragma unroll
        for (int j = 0; j < 2; ++j)
            #pragma unroll
            for (int r = 0; r < 4; ++r)
                h2T[((size_t)b * 1024 + r0 + wm * 64 + i * 16 + q * 4 + r) * 512
                    + n0 + wn * 32 + j * 16 + lm] = f2bf(acc[i][j][r]);
}

// ================ k4_gemm: convT via MFMA + fused bias/relu/residual (unchanged)
__global__ __launch_bounds__(256) void k4_gemm(
    const unsigned short* __restrict__ h2T, const unsigned short* __restrict__ wTt,
    const float* __restrict__ bT, const float* __restrict__ x,
    const float* __restrict__ RZ, float* __restrict__ out)
{
    const int nt = blockIdx.x & 1;
    const int g  = (blockIdx.x >> 1) & 1;
    const int rt = blockIdx.x >> 2;
    const int r0 = rt * 128;
    const int b  = r0 >> 10, lp0 = r0 & 1023;

    __shared__ __align__(16) char smem[65536];
    unsigned short* Asl = (unsigned short*)smem;
    unsigned short* Bsl = Asl + 128 * 64;
    float* epi = (float*)smem;

    const int t = threadIdx.x;
    const int lane = t & 63;
    const int wave = t >> 6;
    const int wm = wave & 1, wn = wave >> 1;
    const int q = lane >> 4, lm = lane & 15;

    f32x4 acc[4][4];
    #pragma unroll
    for (int i = 0; i < 4; ++i)
        #pragma unroll
        for (int j = 0; j < 4; ++j)
            #pragma unroll
            for (int r = 0; r < 4; ++r) acc[i][j][r] = 0.f;

    for (int k0 = 0; k0 < 256; k0 += 64) {
        #pragma unroll
        for (int rd = 0; rd < 4; ++rd) {
            const int e = rd * 2048 + t * 8;
            const int row = e >> 6, col = e & 63;
            const unsigned short* ga = h2T + (size_t)(r0 + row) * 512 + g * 256 + k0 + col;
            __builtin_amdgcn_global_load_lds((gas_u32*)ga, (las_u32*)(Asl + e), 16, 0, 0);
            const unsigned short* gb = wTt + (size_t)g * 65536 + (size_t)(nt * 128 + row) * 256 + k0 + col;
            __builtin_amdgcn_global_load_lds((gas_u32*)gb, (las_u32*)(Bsl + e), 16, 0, 0);
        }
        __syncthreads();
        #pragma unroll
        for (int kk = 0; kk < 2; ++kk) {
            bf16x8 af[4], bf[4];
            #pragma unroll
            for (int i = 0; i < 4; ++i)
                af[i] = *(const bf16x8*)(Asl + (wm * 64 + i * 16 + lm) * 64 + kk * 32 + q * 8);
            #pragma unroll
            for (int j = 0; j < 4; ++j)
                bf[j] = *(const bf16x8*)(Bsl + (wn * 64 + j * 16 + lm) * 64 + kk * 32 + q * 8);
            #pragma unroll
            for (int i = 0; i < 4; ++i)
                #pragma unroll
                for (int j = 0; j < 4; ++j)
                    acc[i][j] = __builtin_amdgcn_mfma_f32_16x16x32_bf16(af[i], bf[j], acc[i][j], 0, 0, 0);
        }
        __syncthreads();
    }

    #pragma unroll
    for (int j = 0; j < 4; ++j) {
        const int col_blk = wn * 64 + j * 16 + lm;
        const int o_l = col_blk >> 1, kk2 = col_blk & 1;
        #pragma unroll
        for (int i = 0; i < 4; ++i) {
            #pragma unroll
            for (int r = 0; r < 4; ++r) {
                const int row_l = wm * 64 + i * 16 + q * 4 + r;
                const int l_l = 2 * row_l + kk2;
                const int chunk = ((l_l >> 2) + o_l) & 63;
                epi[o_l * 256 + chunk * 4 + (l_l & 3)] = acc[i][j][r];
            }
        }
    }
    __syncthreads();
    const int row = t >> 2, quad = t & 3;
    const int c = g * 128 + nt * 64 + row;
    const float bias = bT[c];
    const float rz = RZ[0];
    const size_t gbase = ((size_t)(b * 256 + c)) * 2048 + 2 * lp0 + quad * 64;
    #pragma unroll
    for (int k = 0; k < 16; ++k) {
        const int chunk_phys = (quad * 16 + k + row) & 63;
        const float4 v = *(const float4*)(epi + row * 256 + chunk_phys * 4);
        const float4 xv = *(const float4*)(x + gbase + k * 4);
        float4 o;
        o.x = xv.x + rz * fmaxf(v.x + bias, 0.f);
        o.y = xv.y + rz * fmaxf(v.y + bias, 0.f);
        o.z = xv.z + rz * fmaxf(v.z + bias, 0.f);
        o.w = xv.w + rz * fmaxf(v.w + bias, 0.f);
        *(float4*)(out + gbase + k * 4) = o;
    }
}

extern "C" void kernel_launch(void* const* d_in, const int* in_sizes, int n_in,
                              void* d_out, int out_size, void* d_ws, size_t ws_size,
                              hipStream_t stream) {
    (void)in_sizes; (void)n_in; (void)out_size; (void)ws_size;
    const float* x  = (const float*)d_in[0];
    const float* w1 = (const float*)d_in[1];
    const float* b1 = (const float*)d_in[2];
    const float* P  = (const float*)d_in[3];
    const float* wT = (const float*)d_in[4];
    const float* bT = (const float*)d_in[5];
    const float* RZ = (const float*)d_in[6];
    float* out = (float*)d_out;

    // workspace (34.25 MB):
    //   [0,16M)   hb  bf16 [8192,1024]
    //   [16,32M)  h2T bf16 [16,1024,512]
    //   [32,33M)  Pb bf16 [512,1024]; [33,34M) Ptb bf16 [1024,512]; [34M..) wTt 256K
    // Sb bf16 [8192,512] (8 MB) lives in d_out (read by gemm_retr_sm before k4 overwrites).
    char* ws = (char*)d_ws;
    unsigned short* hb  = (unsigned short*)ws;
    unsigned short* h2T = (unsigned short*)(ws + (16u << 20));
    unsigned short* Pb  = (unsigned short*)(ws + (32u << 20));
    unsigned short* Ptb = (unsigned short*)(ws + (33u << 20));
    unsigned short* wTt = (unsigned short*)(ws + (34u << 20));
    unsigned short* Sb  = (unsigned short*)out;

    hipLaunchKernelGGL(k_front,      dim3(896), dim3(512), 0, stream,
                       x, w1, b1, P, wT, hb, Pb, Ptb, wTt);
    hipLaunchKernelGGL(gemm_sc,      dim3(256), dim3(512), 0, stream, hb, Pb, Sb);
    hipLaunchKernelGGL(gemm_retr_sm, dim3(512), dim3(512), 0, stream, Ptb, Sb, h2T);
    hipLaunchKernelGGL(k4_gemm,      dim3(512), dim3(256), 0, stream, h2T, wTt, bT, x, RZ, out);
}

// Round 7
// 185.010 us; speedup vs baseline: 1.1040x; 1.1040x over previous
//
#include <hip/hip_runtime.h>

#define NB 16
#define NCIN 256
#define NL 2048
#define NHID 512
#define NM 512
#define NLP 1024

typedef short bf16x8 __attribute__((ext_vector_type(8)));
typedef unsigned short u16x8 __attribute__((ext_vector_type(8)));
typedef float f32x4 __attribute__((ext_vector_type(4)));
typedef __attribute__((address_space(1))) const unsigned int gas_u32;
typedef __attribute__((address_space(3))) unsigned int las_u32;

__device__ __forceinline__ unsigned short f2bf(float f) {
    unsigned int u = __builtin_bit_cast(unsigned int, f);
    return (unsigned short)((u + 0x7FFFu + ((u >> 16) & 1u)) >> 16);
}
__device__ __forceinline__ float bf2f(unsigned short u) {
    return __builtin_bit_cast(float, ((unsigned int)u) << 16);
}

// ================ k_front: conv1x1+bias+relu+pool direct from x (bb<512),
//                  plus P cast/transpose (512..639) and wT transpose (640..895)
__global__ __launch_bounds__(512) void k_front(
    const float* __restrict__ x, const float* __restrict__ w1,
    const float* __restrict__ b1, const float* __restrict__ P,
    const float* __restrict__ wT, unsigned short* __restrict__ hb,
    unsigned short* __restrict__ Pb, unsigned short* __restrict__ Ptb,
    unsigned short* __restrict__ wTt)
{
    __shared__ __align__(16) unsigned short smem[66560];  // 133,120 B
    const int bb = blockIdx.x;
    const int t = threadIdx.x;

    if (bb >= 512) {
        if (bb < 640) {   // P -> Pb (cast) and Ptb (transpose), 64x64 tiles
            unsigned short (*tbuf)[65] = (unsigned short (*)[65])smem;
            const int pb = bb - 512;
            const int mt = pb >> 4, lt = pb & 15;
            for (int i = t; i < 4096; i += 512) {
                const int r = i >> 6, c = i & 63;
                const unsigned short v = f2bf(P[(size_t)(mt * 64 + r) * 1024 + lt * 64 + c]);
                Pb[(size_t)(mt * 64 + r) * 1024 + lt * 64 + c] = v;
                tbuf[c][r] = v;
            }
            __syncthreads();
            for (int i = t; i < 4096; i += 512) {
                const int r = i >> 6, c = i & 63;
                Ptb[(size_t)(lt * 64 + r) * 512 + mt * 64 + c] = tbuf[r][c];
            }
        } else {          // wT -> wTt [g][(o,kk)][i]
            const int t5 = (bb - 640) * 512 + t;   // < 131072
            const int g = t5 >> 16, ok = (t5 >> 8) & 255, i = t5 & 255;
            wTt[t5] = f2bf(wT[(size_t)(g * 256 + i) * 256 + ok]);
        }
        return;
    }

    // ---- conv block: rows r0..r0+127 over (b,l), cols = 256 o of group g
    const int g  = bb & 1;
    const int rt = bb >> 1;
    const int r0 = rt * 128;
    const int b  = r0 >> 11, l0 = r0 & 2047;

    unsigned short* T   = smem;           // [128][136] bf16 (ch, l)
    unsigned short* Asl = smem + 17408;   // [128][128] bf16 (l, ch)
    unsigned short* Bsl = smem + 33792;   // [256][128] bf16 (o, ch)
    unsigned short* epi = smem;           // [256][72]  (reused after MFMA)

    // load x fp32 -> T bf16 [ch][l]
    #pragma unroll
    for (int i3 = 0; i3 < 8; ++i3) {
        const int idx = i3 * 512 + t;
        const int ch = idx >> 5, f4 = idx & 31;
        const float4 v = *(const float4*)(x + ((size_t)(b * 256 + g * 128 + ch)) * 2048 + l0 + f4 * 4);
        ushort4 u;
        u.x = f2bf(v.x); u.y = f2bf(v.y); u.z = f2bf(v.z); u.w = f2bf(v.w);
        *(ushort4*)(T + ch * 136 + f4 * 4) = u;
    }
    // load w1 fp32 -> Bsl bf16 [o][ch]
    #pragma unroll
    for (int i5 = 0; i5 < 16; ++i5) {
        const int idx = i5 * 512 + t;
        const int o = idx >> 5, f4 = idx & 31;
        const float4 v = *(const float4*)(w1 + ((size_t)(g * 256 + o)) * 128 + f4 * 4);
        ushort4 u;
        u.x = f2bf(v.x); u.y = f2bf(v.y); u.z = f2bf(v.z); u.w = f2bf(v.w);
        *(ushort4*)(Bsl + o * 128 + f4 * 4) = u;
    }
    __syncthreads();
    // transpose T[ch][l] -> Asl[l][ch]
    #pragma unroll
    for (int i4 = 0; i4 < 4; ++i4) {
        const int idx = i4 * 512 + t;
        const int ch = idx & 127, lo = idx >> 7;
        const u16x8 v = *(const u16x8*)(T + ch * 136 + lo * 8);
        #pragma unroll
        for (int u2 = 0; u2 < 8; ++u2)
            Asl[(lo * 8 + u2) * 128 + ch] = v[u2];
    }
    __syncthreads();

    const int lane = t & 63, wave = t >> 6;
    const int wm = wave & 1, wn = wave >> 1;      // 2 x 4 waves, tile 64x64
    const int q = lane >> 4, lm = lane & 15;

    f32x4 acc[4][4];
    #pragma unroll
    for (int i = 0; i < 4; ++i)
        #pragma unroll
        for (int j = 0; j < 4; ++j)
            #pragma unroll
            for (int r = 0; r < 4; ++r) acc[i][j][r] = 0.f;

    #pragma unroll
    for (int kc = 0; kc < 4; ++kc) {   // K=128 = 4 x 32
        bf16x8 af[4], bf[4];
        #pragma unroll
        for (int i = 0; i < 4; ++i)
            af[i] = *(const bf16x8*)(Asl + (wm * 64 + i * 16 + lm) * 128 + kc * 32 + q * 8);
        #pragma unroll
        for (int j = 0; j < 4; ++j)
            bf[j] = *(const bf16x8*)(Bsl + (wn * 64 + j * 16 + lm) * 128 + kc * 32 + q * 8);
        #pragma unroll
        for (int i = 0; i < 4; ++i)
            #pragma unroll
            for (int j = 0; j < 4; ++j)
                acc[i][j] = __builtin_amdgcn_mfma_f32_16x16x32_bf16(af[i], bf[j], acc[i][j], 0, 0, 0);
    }
    __syncthreads();   // Asl/Bsl/T dead; epi reuses region

    // epilogue: pool adjacent l (reg pairs) + bias + relu -> epi[o][lp]
    #pragma unroll
    for (int j = 0; j < 4; ++j) {
        const int col = wn * 64 + j * 16 + lm;            // o local [0,256)
        const float bias = b1[g * 256 + col];
        #pragma unroll
        for (int i = 0; i < 4; ++i) {
            const float p0 = fmaxf(fmaxf(acc[i][j][0], acc[i][j][1]) + bias, 0.f);
            const float p1 = fmaxf(fmaxf(acc[i][j][2], acc[i][j][3]) + bias, 0.f);
            const int lp_loc = wm * 32 + i * 8 + q * 2;   // [0,64)
            ushort2 u; u.x = f2bf(p0); u.y = f2bf(p1);
            *(ushort2*)(epi + col * 72 + lp_loc) = u;
        }
    }
    __syncthreads();
    const int c_loc = t >> 1, half = t & 1;
    unsigned short* dst = hb + ((size_t)(b * 512 + g * 256 + c_loc)) * 1024 + (l0 >> 1) + half * 32;
    #pragma unroll
    for (int u = 0; u < 4; ++u)
        *(u16x8*)(dst + u * 8) = *(const u16x8*)(epi + c_loc * 72 + half * 32 + u * 8);
}

// ================ gemm_sc: Sb[8192,512] bf16 = hb . Pb^T   (512 thr, 8 waves)
__global__ __launch_bounds__(512, 2) void gemm_sc(
    const unsigned short* __restrict__ A, const unsigned short* __restrict__ B,
    unsigned short* __restrict__ Sb)
{
    const int nt = blockIdx.x & 3;
    const int rt = blockIdx.x >> 2;
    const int r0 = rt * 128, n0 = nt * 128;

    __shared__ unsigned short Asl[128 * 64];
    __shared__ unsigned short Bsl[128 * 64];

    const int t = threadIdx.x;
    const int lane = t & 63;
    const int wave = t >> 6;
    const int wm = wave & 1, wn = wave >> 1;
    const int q = lane >> 4, lm = lane & 15;

    f32x4 acc[4][2];
    #pragma unroll
    for (int i = 0; i < 4; ++i)
        #pragma unroll
        for (int j = 0; j < 2; ++j)
            #pragma unroll
            for (int r = 0; r < 4; ++r) acc[i][j][r] = 0.f;

    for (int k0 = 0; k0 < 1024; k0 += 64) {
        #pragma unroll
        for (int rd = 0; rd < 2; ++rd) {
            const int e = rd * 4096 + t * 8;
            const int row = e >> 6, col = e & 63;
            const unsigned short* ga = A + (size_t)(r0 + row) * 1024 + k0 + col;
            __builtin_amdgcn_global_load_lds((gas_u32*)ga, (las_u32*)(Asl + e), 16, 0, 0);
            const unsigned short* gb = B + (size_t)(n0 + row) * 1024 + k0 + col;
            __builtin_amdgcn_global_load_lds((gas_u32*)gb, (las_u32*)(Bsl + e), 16, 0, 0);
        }
        __syncthreads();
        #pragma unroll
        for (int kk = 0; kk < 2; ++kk) {
            bf16x8 af[4], bf[2];
            #pragma unroll
            for (int i = 0; i < 4; ++i)
                af[i] = *(const bf16x8*)(Asl + (wm * 64 + i * 16 + lm) * 64 + kk * 32 + q * 8);
            #pragma unroll
            for (int j = 0; j < 2; ++j)
                bf[j] = *(const bf16x8*)(Bsl + (wn * 32 + j * 16 + lm) * 64 + kk * 32 + q * 8);
            #pragma unroll
            for (int i = 0; i < 4; ++i)
                #pragma unroll
                for (int j = 0; j < 2; ++j)
                    acc[i][j] = __builtin_amdgcn_mfma_f32_16x16x32_bf16(af[i], bf[j], acc[i][j], 0, 0, 0);
        }
        __syncthreads();
    }

    #pragma unroll
    for (int i = 0; i < 4; ++i)
        #pragma unroll
        for (int j = 0; j < 2; ++j)
            #pragma unroll
            for (int r = 0; r < 4; ++r)
                Sb[(size_t)(r0 + wm * 64 + i * 16 + q * 4 + r) * 512
                   + n0 + wn * 32 + j * 16 + lm] = f2bf(acc[i][j][r]);
}

// ================ k_softmax: Sb bf16 -> Ab bf16, rows of 512 (8192 rows)
__global__ __launch_bounds__(256) void k_softmax(
    const unsigned short* __restrict__ Sb, unsigned short* __restrict__ Ab)
{
    const int row = blockIdx.x * 4 + (threadIdx.x >> 6);
    const int lane = threadIdx.x & 63;
    const u16x8 uv = *(const u16x8*)(Sb + (size_t)row * 512 + lane * 8);

    float v[8];
    #pragma unroll
    for (int j = 0; j < 8; ++j) v[j] = bf2f(uv[j]);

    float mx = v[0];
    #pragma unroll
    for (int j = 1; j < 8; ++j) mx = fmaxf(mx, v[j]);
    for (int off = 32; off > 0; off >>= 1) mx = fmaxf(mx, __shfl_xor(mx, off));

    float sum = 0.f;
    #pragma unroll
    for (int j = 0; j < 8; ++j) { v[j] = __expf(v[j] - mx); sum += v[j]; }
    for (int off = 32; off > 0; off >>= 1) sum += __shfl_xor(sum, off);

    const float inv = 1.f / sum;
    u16x8 ov;
    #pragma unroll
    for (int j = 0; j < 8; ++j) ov[j] = f2bf(v[j] * inv);
    *(u16x8*)(Ab + (size_t)row * 512 + lane * 8) = ov;
}

// ================ gemm_retr: per-batch h2T[b,lp,c] bf16 = Ptb . attn_b^T (512 thr)
__global__ __launch_bounds__(512, 2) void gemm_retr(
    const unsigned short* __restrict__ Ptb, const unsigned short* __restrict__ Ab,
    unsigned short* __restrict__ h2T)
{
    const int tl = blockIdx.x & 31;
    const int b  = blockIdx.x >> 5;
    const int nt = tl & 3;
    const int rt = tl >> 2;
    const int r0 = rt * 128, n0 = nt * 128;

    __shared__ unsigned short Asl[128 * 64];
    __shared__ unsigned short Bsl[128 * 64];

    const int t = threadIdx.x;
    const int lane = t & 63;
    const int wave = t >> 6;
    const int wm = wave & 1, wn = wave >> 1;
    const int q = lane >> 4, lm = lane & 15;

    f32x4 acc[4][2];
    #pragma unroll
    for (int i = 0; i < 4; ++i)
        #pragma unroll
        for (int j = 0; j < 2; ++j)
            #pragma unroll
            for (int r = 0; r < 4; ++r) acc[i][j][r] = 0.f;

    for (int k0 = 0; k0 < 512; k0 += 64) {
        #pragma unroll
        for (int rd = 0; rd < 2; ++rd) {
            const int e = rd * 4096 + t * 8;
            const int row = e >> 6, col = e & 63;
            const unsigned short* ga = Ptb + (size_t)(r0 + row) * 512 + k0 + col;
            __builtin_amdgcn_global_load_lds((gas_u32*)ga, (las_u32*)(Asl + e), 16, 0, 0);
            const unsigned short* gb = Ab + ((size_t)b * 512 + n0 + row) * 512 + k0 + col;
            __builtin_amdgcn_global_load_lds((gas_u32*)gb, (las_u32*)(Bsl + e), 16, 0, 0);
        }
        __syncthreads();
        #pragma unroll
        for (int kk = 0; kk < 2; ++kk) {
            bf16x8 af[4], bf[2];
            #pragma unroll
            for (int i = 0; i < 4; ++i)
                af[i] = *(const bf16x8*)(Asl + (wm * 64 + i * 16 + lm) * 64 + kk * 32 + q * 8);
            #pragma unroll
            for (int j = 0; j < 2; ++j)
                bf[j] = *(const bf16x8*)(Bsl + (wn * 32 + j * 16 + lm) * 64 + kk * 32 + q * 8);
            #pragma unroll
            for (int i = 0; i < 4; ++i)
                #pragma unroll
                for (int j = 0; j < 2; ++j)
                    acc[i][j] = __builtin_amdgcn_mfma_f32_16x16x32_bf16(af[i], bf[j], acc[i][j], 0, 0, 0);
        }
        __syncthreads();
    }

    #pragma unroll
    for (int i = 0; i < 4; ++i)
        #pragma unroll
        for (int j = 0; j < 2; ++j)
            #pragma unroll
            for (int r = 0; r < 4; ++r)
                h2T[((size_t)b * 1024 + r0 + wm * 64 + i * 16 + q * 4 + r) * 512
                    + n0 + wn * 32 + j * 16 + lm] = f2bf(acc[i][j][r]);
}

// ================ k4_gemm: convT via MFMA + fused bias/relu/residual (unchanged)
__global__ __launch_bounds__(256) void k4_gemm(
    const unsigned short* __restrict__ h2T, const unsigned short* __restrict__ wTt,
    const float* __restrict__ bT, const float* __restrict__ x,
    const float* __restrict__ RZ, float* __restrict__ out)
{
    const int nt = blockIdx.x & 1;
    const int g  = (blockIdx.x >> 1) & 1;
    const int rt = blockIdx.x >> 2;
    const int r0 = rt * 128;
    const int b  = r0 >> 10, lp0 = r0 & 1023;

    __shared__ __align__(16) char smem[65536];
    unsigned short* Asl = (unsigned short*)smem;
    unsigned short* Bsl = Asl + 128 * 64;
    float* epi = (float*)smem;

    const int t = threadIdx.x;
    const int lane = t & 63;
    const int wave = t >> 6;
    const int wm = wave & 1, wn = wave >> 1;
    const int q = lane >> 4, lm = lane & 15;

    f32x4 acc[4][4];
    #pragma unroll
    for (int i = 0; i < 4; ++i)
        #pragma unroll
        for (int j = 0; j < 4; ++j)
            #pragma unroll
            for (int r = 0; r < 4; ++r) acc[i][j][r] = 0.f;

    for (int k0 = 0; k0 < 256; k0 += 64) {
        #pragma unroll
        for (int rd = 0; rd < 4; ++rd) {
            const int e = rd * 2048 + t * 8;
            const int row = e >> 6, col = e & 63;
            const unsigned short* ga = h2T + (size_t)(r0 + row) * 512 + g * 256 + k0 + col;
            __builtin_amdgcn_global_load_lds((gas_u32*)ga, (las_u32*)(Asl + e), 16, 0, 0);
            const unsigned short* gb = wTt + (size_t)g * 65536 + (size_t)(nt * 128 + row) * 256 + k0 + col;
            __builtin_amdgcn_global_load_lds((gas_u32*)gb, (las_u32*)(Bsl + e), 16, 0, 0);
        }
        __syncthreads();
        #pragma unroll
        for (int kk = 0; kk < 2; ++kk) {
            bf16x8 af[4], bf[4];
            #pragma unroll
            for (int i = 0; i < 4; ++i)
                af[i] = *(const bf16x8*)(Asl + (wm * 64 + i * 16 + lm) * 64 + kk * 32 + q * 8);
            #pragma unroll
            for (int j = 0; j < 4; ++j)
                bf[j] = *(const bf16x8*)(Bsl + (wn * 64 + j * 16 + lm) * 64 + kk * 32 + q * 8);
            #pragma unroll
            for (int i = 0; i < 4; ++i)
                #pragma unroll
                for (int j = 0; j < 4; ++j)
                    acc[i][j] = __builtin_amdgcn_mfma_f32_16x16x32_bf16(af[i], bf[j], acc[i][j], 0, 0, 0);
        }
        __syncthreads();
    }

    #pragma unroll
    for (int j = 0; j < 4; ++j) {
        const int col_blk = wn * 64 + j * 16 + lm;
        const int o_l = col_blk >> 1, kk2 = col_blk & 1;
        #pragma unroll
        for (int i = 0; i < 4; ++i) {
            #pragma unroll
            for (int r = 0; r < 4; ++r) {
                const int row_l = wm * 64 + i * 16 + q * 4 + r;
                const int l_l = 2 * row_l + kk2;
                const int chunk = ((l_l >> 2) + o_l) & 63;
                epi[o_l * 256 + chunk * 4 + (l_l & 3)] = acc[i][j][r];
            }
        }
    }
    __syncthreads();
    const int row = t >> 2, quad = t & 3;
    const int c = g * 128 + nt * 64 + row;
    const float bias = bT[c];
    const float rz = RZ[0];
    const size_t gbase = ((size_t)(b * 256 + c)) * 2048 + 2 * lp0 + quad * 64;
    #pragma unroll
    for (int k = 0; k < 16; ++k) {
        const int chunk_phys = (quad * 16 + k + row) & 63;
        const float4 v = *(const float4*)(epi + row * 256 + chunk_phys * 4);
        const float4 xv = *(const float4*)(x + gbase + k * 4);
        float4 o;
        o.x = xv.x + rz * fmaxf(v.x + bias, 0.f);
        o.y = xv.y + rz * fmaxf(v.y + bias, 0.f);
        o.z = xv.z + rz * fmaxf(v.z + bias, 0.f);
        o.w = xv.w + rz * fmaxf(v.w + bias, 0.f);
        *(float4*)(out + gbase + k * 4) = o;
    }
}

extern "C" void kernel_launch(void* const* d_in, const int* in_sizes, int n_in,
                              void* d_out, int out_size, void* d_ws, size_t ws_size,
                              hipStream_t stream) {
    (void)in_sizes; (void)n_in; (void)out_size; (void)ws_size;
    const float* x  = (const float*)d_in[0];
    const float* w1 = (const float*)d_in[1];
    const float* b1 = (const float*)d_in[2];
    const float* P  = (const float*)d_in[3];
    const float* wT = (const float*)d_in[4];
    const float* bT = (const float*)d_in[5];
    const float* RZ = (const float*)d_in[6];
    float* out = (float*)d_out;

    // workspace (34.25 MB):
    //   [0,16M)   hb  bf16 [8192,1024] (dead after gemm_sc) -> Ab bf16 [8192,512] (softmax->retr)
    //   [16,32M)  h2T bf16 [16,1024,512]
    //   [32,33M)  Pb bf16 [512,1024]; [33,34M) Ptb bf16 [1024,512]; [34M..) wTt 256K
    // Sb bf16 [8192,512] (8 MB) lives in d_out (dead before k4 overwrites out).
    char* ws = (char*)d_ws;
    unsigned short* hb  = (unsigned short*)ws;
    unsigned short* Ab  = (unsigned short*)ws;
    unsigned short* h2T = (unsigned short*)(ws + (16u << 20));
    unsigned short* Pb  = (unsigned short*)(ws + (32u << 20));
    unsigned short* Ptb = (unsigned short*)(ws + (33u << 20));
    unsigned short* wTt = (unsigned short*)(ws + (34u << 20));
    unsigned short* Sb  = (unsigned short*)out;

    hipLaunchKernelGGL(k_front,   dim3(896),  dim3(512), 0, stream,
                       x, w1, b1, P, wT, hb, Pb, Ptb, wTt);
    hipLaunchKernelGGL(gemm_sc,   dim3(256),  dim3(512), 0, stream, hb, Pb, Sb);
    hipLaunchKernelGGL(k_softmax, dim3(2048), dim3(256), 0, stream, Sb, Ab);
    hipLaunchKernelGGL(gemm_retr, dim3(512),  dim3(512), 0, stream, Ptb, Ab, h2T);
    hipLaunchKernelGGL(k4_gemm,   dim3(512),  dim3(256), 0, stream, h2T, wTt, bT, x, RZ, out);
}

// Round 8
// 182.762 us; speedup vs baseline: 1.1176x; 1.0123x over previous
//
#include <hip/hip_runtime.h>

#define NB 16
#define NCIN 256
#define NL 2048
#define NHID 512
#define NM 512
#define NLP 1024

typedef short bf16x8 __attribute__((ext_vector_type(8)));
typedef unsigned short u16x8 __attribute__((ext_vector_type(8)));
typedef float f32x4 __attribute__((ext_vector_type(4)));
typedef __attribute__((address_space(1))) const unsigned int gas_u32;
typedef __attribute__((address_space(3))) unsigned int las_u32;

__device__ __forceinline__ unsigned short f2bf(float f) {
    unsigned int u = __builtin_bit_cast(unsigned int, f);
    return (unsigned short)((u + 0x7FFFu + ((u >> 16) & 1u)) >> 16);
}
__device__ __forceinline__ float bf2f(unsigned short u) {
    return __builtin_bit_cast(float, ((unsigned int)u) << 16);
}

// ================ k_front: conv1x1+bias+relu+pool direct from x (bb<512),
//                  plus P cast/transpose (512..639) and wT transpose (640..895)
__global__ __launch_bounds__(512) void k_front(
    const float* __restrict__ x, const float* __restrict__ w1,
    const float* __restrict__ b1, const float* __restrict__ P,
    const float* __restrict__ wT, unsigned short* __restrict__ hb,
    unsigned short* __restrict__ Pb, unsigned short* __restrict__ Ptb,
    unsigned short* __restrict__ wTt)
{
    __shared__ __align__(16) unsigned short smem[66560];  // 133,120 B
    const int bb = blockIdx.x;
    const int t = threadIdx.x;

    if (bb >= 512) {
        if (bb < 640) {   // P -> Pb (cast) and Ptb (transpose), 64x64 tiles
            unsigned short (*tbuf)[65] = (unsigned short (*)[65])smem;
            const int pb = bb - 512;
            const int mt = pb >> 4, lt = pb & 15;
            for (int i = t; i < 4096; i += 512) {
                const int r = i >> 6, c = i & 63;
                const unsigned short v = f2bf(P[(size_t)(mt * 64 + r) * 1024 + lt * 64 + c]);
                Pb[(size_t)(mt * 64 + r) * 1024 + lt * 64 + c] = v;
                tbuf[c][r] = v;
            }
            __syncthreads();
            for (int i = t; i < 4096; i += 512) {
                const int r = i >> 6, c = i & 63;
                Ptb[(size_t)(lt * 64 + r) * 512 + mt * 64 + c] = tbuf[r][c];
            }
        } else {          // wT -> wTt [g][(o,kk)][i]
            const int t5 = (bb - 640) * 512 + t;   // < 131072
            const int g = t5 >> 16, ok = (t5 >> 8) & 255, i = t5 & 255;
            wTt[t5] = f2bf(wT[(size_t)(g * 256 + i) * 256 + ok]);
        }
        return;
    }

    // ---- conv block: rows r0..r0+127 over (b,l), cols = 256 o of group g
    const int g  = bb & 1;
    const int rt = bb >> 1;
    const int r0 = rt * 128;
    const int b  = r0 >> 11, l0 = r0 & 2047;

    unsigned short* T   = smem;           // [128][136] bf16 (ch, l)
    unsigned short* Asl = smem + 17408;   // [128][128] bf16 (l, ch)
    unsigned short* Bsl = smem + 33792;   // [256][128] bf16 (o, ch)
    unsigned short* epi = smem;           // [256][72]  (reused after MFMA)

    // load x fp32 -> T bf16 [ch][l]
    #pragma unroll
    for (int i3 = 0; i3 < 8; ++i3) {
        const int idx = i3 * 512 + t;
        const int ch = idx >> 5, f4 = idx & 31;
        const float4 v = *(const float4*)(x + ((size_t)(b * 256 + g * 128 + ch)) * 2048 + l0 + f4 * 4);
        ushort4 u;
        u.x = f2bf(v.x); u.y = f2bf(v.y); u.z = f2bf(v.z); u.w = f2bf(v.w);
        *(ushort4*)(T + ch * 136 + f4 * 4) = u;
    }
    // load w1 fp32 -> Bsl bf16 [o][ch]
    #pragma unroll
    for (int i5 = 0; i5 < 16; ++i5) {
        const int idx = i5 * 512 + t;
        const int o = idx >> 5, f4 = idx & 31;
        const float4 v = *(const float4*)(w1 + ((size_t)(g * 256 + o)) * 128 + f4 * 4);
        ushort4 u;
        u.x = f2bf(v.x); u.y = f2bf(v.y); u.z = f2bf(v.z); u.w = f2bf(v.w);
        *(ushort4*)(Bsl + o * 128 + f4 * 4) = u;
    }
    __syncthreads();
    // transpose T[ch][l] -> Asl[l][ch]
    #pragma unroll
    for (int i4 = 0; i4 < 4; ++i4) {
        const int idx = i4 * 512 + t;
        const int ch = idx & 127, lo = idx >> 7;
        const u16x8 v = *(const u16x8*)(T + ch * 136 + lo * 8);
        #pragma unroll
        for (int u2 = 0; u2 < 8; ++u2)
            Asl[(lo * 8 + u2) * 128 + ch] = v[u2];
    }
    __syncthreads();

    const int lane = t & 63, wave = t >> 6;
    const int wm = wave & 1, wn = wave >> 1;      // 2 x 4 waves, tile 64x64
    const int q = lane >> 4, lm = lane & 15;

    f32x4 acc[4][4];
    #pragma unroll
    for (int i = 0; i < 4; ++i)
        #pragma unroll
        for (int j = 0; j < 4; ++j)
            #pragma unroll
            for (int r = 0; r < 4; ++r) acc[i][j][r] = 0.f;

    #pragma unroll
    for (int kc = 0; kc < 4; ++kc) {   // K=128 = 4 x 32
        bf16x8 af[4], bf[4];
        #pragma unroll
        for (int i = 0; i < 4; ++i)
            af[i] = *(const bf16x8*)(Asl + (wm * 64 + i * 16 + lm) * 128 + kc * 32 + q * 8);
        #pragma unroll
        for (int j = 0; j < 4; ++j)
            bf[j] = *(const bf16x8*)(Bsl + (wn * 64 + j * 16 + lm) * 128 + kc * 32 + q * 8);
        #pragma unroll
        for (int i = 0; i < 4; ++i)
            #pragma unroll
            for (int j = 0; j < 4; ++j)
                acc[i][j] = __builtin_amdgcn_mfma_f32_16x16x32_bf16(af[i], bf[j], acc[i][j], 0, 0, 0);
    }
    __syncthreads();   // Asl/Bsl/T dead; epi reuses region

    // epilogue: pool adjacent l (reg pairs) + bias + relu -> epi[o][lp]
    #pragma unroll
    for (int j = 0; j < 4; ++j) {
        const int col = wn * 64 + j * 16 + lm;            // o local [0,256)
        const float bias = b1[g * 256 + col];
        #pragma unroll
        for (int i = 0; i < 4; ++i) {
            const float p0 = fmaxf(fmaxf(acc[i][j][0], acc[i][j][1]) + bias, 0.f);
            const float p1 = fmaxf(fmaxf(acc[i][j][2], acc[i][j][3]) + bias, 0.f);
            const int lp_loc = wm * 32 + i * 8 + q * 2;   // [0,64)
            ushort2 u; u.x = f2bf(p0); u.y = f2bf(p1);
            *(ushort2*)(epi + col * 72 + lp_loc) = u;
        }
    }
    __syncthreads();
    const int c_loc = t >> 1, half = t & 1;
    unsigned short* dst = hb + ((size_t)(b * 512 + g * 256 + c_loc)) * 1024 + (l0 >> 1) + half * 32;
    #pragma unroll
    for (int u = 0; u < 4; ++u)
        *(u16x8*)(dst + u * 8) = *(const u16x8*)(epi + c_loc * 72 + half * 32 + u * 8);
}

// ================ gemm_sc: Sb[8192,512] bf16 = hb . Pb^T
// 128x64 tile, 256 thr (4 waves, wave-tile 64x32), grid 512 -> 2 blocks/CU
__global__ __launch_bounds__(256, 4) void gemm_sc(
    const unsigned short* __restrict__ A, const unsigned short* __restrict__ B,
    unsigned short* __restrict__ Sb)
{
    const int nt = blockIdx.x & 7;
    const int rt = blockIdx.x >> 3;
    const int r0 = rt * 128, n0 = nt * 64;

    __shared__ unsigned short Asl[128 * 64];
    __shared__ unsigned short Bsl[64 * 64];

    const int t = threadIdx.x;
    const int lane = t & 63;
    const int wave = t >> 6;
    const int wm = wave & 1, wn = wave >> 1;   // 2 x 2: 64-row half, 32-col half
    const int q = lane >> 4, lm = lane & 15;

    f32x4 acc[4][2];
    #pragma unroll
    for (int i = 0; i < 4; ++i)
        #pragma unroll
        for (int j = 0; j < 2; ++j)
            #pragma unroll
            for (int r = 0; r < 4; ++r) acc[i][j][r] = 0.f;

    for (int k0 = 0; k0 < 1024; k0 += 64) {
        #pragma unroll
        for (int rd = 0; rd < 4; ++rd) {   // A: 128x64
            const int e = rd * 2048 + t * 8;
            const int row = e >> 6, col = e & 63;
            const unsigned short* ga = A + (size_t)(r0 + row) * 1024 + k0 + col;
            __builtin_amdgcn_global_load_lds((gas_u32*)ga, (las_u32*)(Asl + e), 16, 0, 0);
        }
        #pragma unroll
        for (int rd = 0; rd < 2; ++rd) {   // B: 64x64
            const int e = rd * 2048 + t * 8;
            const int row = e >> 6, col = e & 63;
            const unsigned short* gb = B + (size_t)(n0 + row) * 1024 + k0 + col;
            __builtin_amdgcn_global_load_lds((gas_u32*)gb, (las_u32*)(Bsl + e), 16, 0, 0);
        }
        __syncthreads();
        #pragma unroll
        for (int kk = 0; kk < 2; ++kk) {
            bf16x8 af[4], bf[2];
            #pragma unroll
            for (int i = 0; i < 4; ++i)
                af[i] = *(const bf16x8*)(Asl + (wm * 64 + i * 16 + lm) * 64 + kk * 32 + q * 8);
            #pragma unroll
            for (int j = 0; j < 2; ++j)
                bf[j] = *(const bf16x8*)(Bsl + (wn * 32 + j * 16 + lm) * 64 + kk * 32 + q * 8);
            #pragma unroll
            for (int i = 0; i < 4; ++i)
                #pragma unroll
                for (int j = 0; j < 2; ++j)
                    acc[i][j] = __builtin_amdgcn_mfma_f32_16x16x32_bf16(af[i], bf[j], acc[i][j], 0, 0, 0);
        }
        __syncthreads();
    }

    #pragma unroll
    for (int i = 0; i < 4; ++i)
        #pragma unroll
        for (int j = 0; j < 2; ++j)
            #pragma unroll
            for (int r = 0; r < 4; ++r)
                Sb[(size_t)(r0 + wm * 64 + i * 16 + q * 4 + r) * 512
                   + n0 + wn * 32 + j * 16 + lm] = f2bf(acc[i][j][r]);
}

// ================ k_softmax: Sb bf16 -> Ab bf16, rows of 512 (8192 rows)
__global__ __launch_bounds__(256) void k_softmax(
    const unsigned short* __restrict__ Sb, unsigned short* __restrict__ Ab)
{
    const int row = blockIdx.x * 4 + (threadIdx.x >> 6);
    const int lane = threadIdx.x & 63;
    const u16x8 uv = *(const u16x8*)(Sb + (size_t)row * 512 + lane * 8);

    float v[8];
    #pragma unroll
    for (int j = 0; j < 8; ++j) v[j] = bf2f(uv[j]);

    float mx = v[0];
    #pragma unroll
    for (int j = 1; j < 8; ++j) mx = fmaxf(mx, v[j]);
    for (int off = 32; off > 0; off >>= 1) mx = fmaxf(mx, __shfl_xor(mx, off));

    float sum = 0.f;
    #pragma unroll
    for (int j = 0; j < 8; ++j) { v[j] = __expf(v[j] - mx); sum += v[j]; }
    for (int off = 32; off > 0; off >>= 1) sum += __shfl_xor(sum, off);

    const float inv = 1.f / sum;
    u16x8 ov;
    #pragma unroll
    for (int j = 0; j < 8; ++j) ov[j] = f2bf(v[j] * inv);
    *(u16x8*)(Ab + (size_t)row * 512 + lane * 8) = ov;
}

// ================ gemm_retr: per-batch h2T[b,lp,c] bf16 = Ptb . attn_b^T
// 128x64 tile, 256 thr (4 waves), grid 1024 -> 4 blocks/CU
__global__ __launch_bounds__(256, 4) void gemm_retr(
    const unsigned short* __restrict__ Ptb, const unsigned short* __restrict__ Ab,
    unsigned short* __restrict__ h2T)
{
    const int tl = blockIdx.x & 63;
    const int b  = blockIdx.x >> 6;
    const int nt = tl & 7;
    const int rt = tl >> 3;
    const int r0 = rt * 128, n0 = nt * 64;

    __shared__ unsigned short Asl[128 * 64];
    __shared__ unsigned short Bsl[64 * 64];

    const int t = threadIdx.x;
    const int lane = t & 63;
    const int wave = t >> 6;
    const int wm = wave & 1, wn = wave >> 1;
    const int q = lane >> 4, lm = lane & 15;

    f32x4 acc[4][2];
    #pragma unroll
    for (int i = 0; i < 4; ++i)
        #pragma unroll
        for (int j = 0; j < 2; ++j)
            #pragma unroll
            for (int r = 0; r < 4; ++r) acc[i][j][r] = 0.f;

    for (int k0 = 0; k0 < 512; k0 += 64) {
        #pragma unroll
        for (int rd = 0; rd < 4; ++rd) {   // A: 128x64 of Ptb
            const int e = rd * 2048 + t * 8;
            const int row = e >> 6, col = e & 63;
            const unsigned short* ga = Ptb + (size_t)(r0 + row) * 512 + k0 + col;
            __builtin_amdgcn_global_load_lds((gas_u32*)ga, (las_u32*)(Asl + e), 16, 0, 0);
        }
        #pragma unroll
        for (int rd = 0; rd < 2; ++rd) {   // B: 64x64 of attn
            const int e = rd * 2048 + t * 8;
            const int row = e >> 6, col = e & 63;
            const unsigned short* gb = Ab + ((size_t)b * 512 + n0 + row) * 512 + k0 + col;
            __builtin_amdgcn_global_load_lds((gas_u32*)gb, (las_u32*)(Bsl + e), 16, 0, 0);
        }
        __syncthreads();
        #pragma unroll
        for (int kk = 0; kk < 2; ++kk) {
            bf16x8 af[4], bf[2];
            #pragma unroll
            for (int i = 0; i < 4; ++i)
                af[i] = *(const bf16x8*)(Asl + (wm * 64 + i * 16 + lm) * 64 + kk * 32 + q * 8);
            #pragma unroll
            for (int j = 0; j < 2; ++j)
                bf[j] = *(const bf16x8*)(Bsl + (wn * 32 + j * 16 + lm) * 64 + kk * 32 + q * 8);
            #pragma unroll
            for (int i = 0; i < 4; ++i)
                #pragma unroll
                for (int j = 0; j < 2; ++j)
                    acc[i][j] = __builtin_amdgcn_mfma_f32_16x16x32_bf16(af[i], bf[j], acc[i][j], 0, 0, 0);
        }
        __syncthreads();
    }

    #pragma unroll
    for (int i = 0; i < 4; ++i)
        #pragma unroll
        for (int j = 0; j < 2; ++j)
            #pragma unroll
            for (int r = 0; r < 4; ++r)
                h2T[((size_t)b * 1024 + r0 + wm * 64 + i * 16 + q * 4 + r) * 512
                    + n0 + wn * 32 + j * 16 + lm] = f2bf(acc[i][j][r]);
}

// ================ k4_gemm: convT via MFMA + fused bias/relu/residual (unchanged)
__global__ __launch_bounds__(256) void k4_gemm(
    const unsigned short* __restrict__ h2T, const unsigned short* __restrict__ wTt,
    const float* __restrict__ bT, const float* __restrict__ x,
    const float* __restrict__ RZ, float* __restrict__ out)
{
    const int nt = blockIdx.x & 1;
    const int g  = (blockIdx.x >> 1) & 1;
    const int rt = blockIdx.x >> 2;
    const int r0 = rt * 128;
    const int b  = r0 >> 10, lp0 = r0 & 1023;

    __shared__ __align__(16) char smem[65536];
    unsigned short* Asl = (unsigned short*)smem;
    unsigned short* Bsl = Asl + 128 * 64;
    float* epi = (float*)smem;

    const int t = threadIdx.x;
    const int lane = t & 63;
    const int wave = t >> 6;
    const int wm = wave & 1, wn = wave >> 1;
    const int q = lane >> 4, lm = lane & 15;

    f32x4 acc[4][4];
    #pragma unroll
    for (int i = 0; i < 4; ++i)
        #pragma unroll
        for (int j = 0; j < 4; ++j)
            #pragma unroll
            for (int r = 0; r < 4; ++r) acc[i][j][r] = 0.f;

    for (int k0 = 0; k0 < 256; k0 += 64) {
        #pragma unroll
        for (int rd = 0; rd < 4; ++rd) {
            const int e = rd * 2048 + t * 8;
            const int row = e >> 6, col = e & 63;
            const unsigned short* ga = h2T + (size_t)(r0 + row) * 512 + g * 256 + k0 + col;
            __builtin_amdgcn_global_load_lds((gas_u32*)ga, (las_u32*)(Asl + e), 16, 0, 0);
            const unsigned short* gb = wTt + (size_t)g * 65536 + (size_t)(nt * 128 + row) * 256 + k0 + col;
            __builtin_amdgcn_global_load_lds((gas_u32*)gb, (las_u32*)(Bsl + e), 16, 0, 0);
        }
        __syncthreads();
        #pragma unroll
        for (int kk = 0; kk < 2; ++kk) {
            bf16x8 af[4], bf[4];
            #pragma unroll
            for (int i = 0; i < 4; ++i)
                af[i] = *(const bf16x8*)(Asl + (wm * 64 + i * 16 + lm) * 64 + kk * 32 + q * 8);
            #pragma unroll
            for (int j = 0; j < 4; ++j)
                bf[j] = *(const bf16x8*)(Bsl + (wn * 64 + j * 16 + lm) * 64 + kk * 32 + q * 8);
            #pragma unroll
            for (int i = 0; i < 4; ++i)
                #pragma unroll
                for (int j = 0; j < 4; ++j)
                    acc[i][j] = __builtin_amdgcn_mfma_f32_16x16x32_bf16(af[i], bf[j], acc[i][j], 0, 0, 0);
        }
        __syncthreads();
    }

    #pragma unroll
    for (int j = 0; j < 4; ++j) {
        const int col_blk = wn * 64 + j * 16 + lm;
        const int o_l = col_blk >> 1, kk2 = col_blk & 1;
        #pragma unroll
        for (int i = 0; i < 4; ++i) {
            #pragma unroll
            for (int r = 0; r < 4; ++r) {
                const int row_l = wm * 64 + i * 16 + q * 4 + r;
                const int l_l = 2 * row_l + kk2;
                const int chunk = ((l_l >> 2) + o_l) & 63;
                epi[o_l * 256 + chunk * 4 + (l_l & 3)] = acc[i][j][r];
            }
        }
    }
    __syncthreads();
    const int row = t >> 2, quad = t & 3;
    const int c = g * 128 + nt * 64 + row;
    const float bias = bT[c];
    const float rz = RZ[0];
    const size_t gbase = ((size_t)(b * 256 + c)) * 2048 + 2 * lp0 + quad * 64;
    #pragma unroll
    for (int k = 0; k < 16; ++k) {
        const int chunk_phys = (quad * 16 + k + row) & 63;
        const float4 v = *(const float4*)(epi + row * 256 + chunk_phys * 4);
        const float4 xv = *(const float4*)(x + gbase + k * 4);
        float4 o;
        o.x = xv.x + rz * fmaxf(v.x + bias, 0.f);
        o.y = xv.y + rz * fmaxf(v.y + bias, 0.f);
        o.z = xv.z + rz * fmaxf(v.z + bias, 0.f);
        o.w = xv.w + rz * fmaxf(v.w + bias, 0.f);
        *(float4*)(out + gbase + k * 4) = o;
    }
}

extern "C" void kernel_launch(void* const* d_in, const int* in_sizes, int n_in,
                              void* d_out, int out_size, void* d_ws, size_t ws_size,
                              hipStream_t stream) {
    (void)in_sizes; (void)n_in; (void)out_size; (void)ws_size;
    const float* x  = (const float*)d_in[0];
    const float* w1 = (const float*)d_in[1];
    const float* b1 = (const float*)d_in[2];
    const float* P  = (const float*)d_in[3];
    const float* wT = (const float*)d_in[4];
    const float* bT = (const float*)d_in[5];
    const float* RZ = (const float*)d_in[6];
    float* out = (float*)d_out;

    // workspace (34.25 MB):
    //   [0,16M)   hb  bf16 [8192,1024] (dead after gemm_sc) -> Ab bf16 [8192,512] (softmax->retr)
    //   [16,32M)  h2T bf16 [16,1024,512]
    //   [32,33M)  Pb bf16 [512,1024]; [33,34M) Ptb bf16 [1024,512]; [34M..) wTt 256K
    // Sb bf16 [8192,512] (8 MB) lives in d_out (dead before k4 overwrites out).
    char* ws = (char*)d_ws;
    unsigned short* hb  = (unsigned short*)ws;
    unsigned short* Ab  = (unsigned short*)ws;
    unsigned short* h2T = (unsigned short*)(ws + (16u << 20));
    unsigned short* Pb  = (unsigned short*)(ws + (32u << 20));
    unsigned short* Ptb = (unsigned short*)(ws + (33u << 20));
    unsigned short* wTt = (unsigned short*)(ws + (34u << 20));
    unsigned short* Sb  = (unsigned short*)out;

    hipLaunchKernelGGL(k_front,   dim3(896),  dim3(512), 0, stream,
                       x, w1, b1, P, wT, hb, Pb, Ptb, wTt);
    hipLaunchKernelGGL(gemm_sc,   dim3(512),  dim3(256), 0, stream, hb, Pb, Sb);
    hipLaunchKernelGGL(k_softmax, dim3(2048), dim3(256), 0, stream, Sb, Ab);
    hipLaunchKernelGGL(gemm_retr, dim3(1024), dim3(256), 0, stream, Ptb, Ab, h2T);
    hipLaunchKernelGGL(k4_gemm,   dim3(512),  dim3(256), 0, stream, h2T, wTt, bT, x, RZ, out);
}

// Round 9
// 161.548 us; speedup vs baseline: 1.2643x; 1.1313x over previous
//
#include <hip/hip_runtime.h>

#define NB 16
#define NCIN 256
#define NL 2048
#define NHID 512
#define NM 512
#define NLP 1024

typedef short bf16x8 __attribute__((ext_vector_type(8)));
typedef unsigned short u16x8 __attribute__((ext_vector_type(8)));
typedef float f32x4 __attribute__((ext_vector_type(4)));
typedef int i32x8 __attribute__((ext_vector_type(8)));
typedef __attribute__((address_space(1))) const unsigned int gas_u32;
typedef __attribute__((address_space(3))) unsigned int las_u32;

#define SC_UNIT 0x7F7F7F7F   // e8m0 127 -> 2^0
#define SC_M6   0x79797979   // e8m0 121 -> 2^-6 (operand pre-scaled by 64)
#define SC_M4   0x7B7B7B7B   // e8m0 123 -> 2^-4 (operand pre-scaled by 16)

__device__ __forceinline__ unsigned short f2bf(float f) {
    unsigned int u = __builtin_bit_cast(unsigned int, f);
    return (unsigned short)((u + 0x7FFFu + ((u >> 16) & 1u)) >> 16);
}
__device__ __forceinline__ float bf2f(unsigned short u) {
    return __builtin_bit_cast(float, ((unsigned int)u) << 16);
}
__device__ __forceinline__ unsigned short f2fp8x2(float a, float b) {
    return (unsigned short)(__builtin_amdgcn_cvt_pk_fp8_f32(a, b, 0, false) & 0xFFFF);
}
__device__ __forceinline__ unsigned char f2fp8(float a) {
    return (unsigned char)(__builtin_amdgcn_cvt_pk_fp8_f32(a, 0.f, 0, false) & 0xFF);
}
__device__ __forceinline__ int f2fp8x4(float a, float b, float c, float d) {
    int w = __builtin_amdgcn_cvt_pk_fp8_f32(a, b, 0, false);
    w = __builtin_amdgcn_cvt_pk_fp8_f32(c, d, w, true);
    return w;
}

// ================ k_front: conv1x1+bias+relu+pool direct from x (bb<512) -> hb fp8,
//                  plus P cast(x64)/transpose -> fp8 (512..639) and wT -> bf16 (640..895)
__global__ __launch_bounds__(512) void k_front(
    const float* __restrict__ x, const float* __restrict__ w1,
    const float* __restrict__ b1, const float* __restrict__ P,
    const float* __restrict__ wT, unsigned char* __restrict__ hb8,
    unsigned char* __restrict__ Pb8, unsigned char* __restrict__ Ptb8,
    unsigned short* __restrict__ wTt)
{
    __shared__ __align__(16) unsigned short smem[66560];  // 133,120 B
    const int bb = blockIdx.x;
    const int t = threadIdx.x;

    if (bb >= 512) {
        if (bb < 640) {   // P*64 -> Pb8 (cast) and Ptb8 (transpose), 64x64 tiles
            unsigned char (*tbuf)[65] = (unsigned char (*)[65])smem;
            const int pb = bb - 512;
            const int mt = pb >> 4, lt = pb & 15;
            for (int i = t; i < 4096; i += 512) {
                const int r = i >> 6, c = i & 63;
                const unsigned char v = f2fp8(P[(size_t)(mt * 64 + r) * 1024 + lt * 64 + c] * 64.f);
                Pb8[(size_t)(mt * 64 + r) * 1024 + lt * 64 + c] = v;
                tbuf[c][r] = v;
            }
            __syncthreads();
            for (int i = t; i < 4096; i += 512) {
                const int r = i >> 6, c = i & 63;
                Ptb8[(size_t)(lt * 64 + r) * 512 + mt * 64 + c] = tbuf[r][c];
            }
        } else {          // wT -> wTt [g][(o,kk)][i] bf16
            const int t5 = (bb - 640) * 512 + t;   // < 131072
            const int g = t5 >> 16, ok = (t5 >> 8) & 255, i = t5 & 255;
            wTt[t5] = f2bf(wT[(size_t)(g * 256 + i) * 256 + ok]);
        }
        return;
    }

    // ---- conv block: rows r0..r0+127 over (b,l), cols = 256 o of group g
    const int g  = bb & 1;
    const int rt = bb >> 1;
    const int r0 = rt * 128;
    const int b  = r0 >> 11, l0 = r0 & 2047;

    unsigned short* T   = smem;           // [128][136] bf16 (ch, l)
    unsigned short* Asl = smem + 17408;   // [128][128] bf16 (l, ch)
    unsigned short* Bsl = smem + 33792;   // [256][128] bf16 (o, ch)
    unsigned char*  epi = (unsigned char*)smem;  // [256][80] fp8 (reused after MFMA)

    // load x fp32 -> T bf16 [ch][l]
    #pragma unroll
    for (int i3 = 0; i3 < 8; ++i3) {
        const int idx = i3 * 512 + t;
        const int ch = idx >> 5, f4 = idx & 31;
        const float4 v = *(const float4*)(x + ((size_t)(b * 256 + g * 128 + ch)) * 2048 + l0 + f4 * 4);
        ushort4 u;
        u.x = f2bf(v.x); u.y = f2bf(v.y); u.z = f2bf(v.z); u.w = f2bf(v.w);
        *(ushort4*)(T + ch * 136 + f4 * 4) = u;
    }
    // load w1 fp32 -> Bsl bf16 [o][ch]
    #pragma unroll
    for (int i5 = 0; i5 < 16; ++i5) {
        const int idx = i5 * 512 + t;
        const int o = idx >> 5, f4 = idx & 31;
        const float4 v = *(const float4*)(w1 + ((size_t)(g * 256 + o)) * 128 + f4 * 4);
        ushort4 u;
        u.x = f2bf(v.x); u.y = f2bf(v.y); u.z = f2bf(v.z); u.w = f2bf(v.w);
        *(ushort4*)(Bsl + o * 128 + f4 * 4) = u;
    }
    __syncthreads();
    // transpose T[ch][l] -> Asl[l][ch]
    #pragma unroll
    for (int i4 = 0; i4 < 4; ++i4) {
        const int idx = i4 * 512 + t;
        const int ch = idx & 127, lo = idx >> 7;
        const u16x8 v = *(const u16x8*)(T + ch * 136 + lo * 8);
        #pragma unroll
        for (int u2 = 0; u2 < 8; ++u2)
            Asl[(lo * 8 + u2) * 128 + ch] = v[u2];
    }
    __syncthreads();

    const int lane = t & 63, wave = t >> 6;
    const int wm = wave & 1, wn = wave >> 1;      // 2 x 4 waves, tile 64x64
    const int q = lane >> 4, lm = lane & 15;

    f32x4 acc[4][4];
    #pragma unroll
    for (int i = 0; i < 4; ++i)
        #pragma unroll
        for (int j = 0; j < 4; ++j)
            #pragma unroll
            for (int r = 0; r < 4; ++r) acc[i][j][r] = 0.f;

    #pragma unroll
    for (int kc = 0; kc < 4; ++kc) {   // K=128 = 4 x 32
        bf16x8 af[4], bf[4];
        #pragma unroll
        for (int i = 0; i < 4; ++i)
            af[i] = *(const bf16x8*)(Asl + (wm * 64 + i * 16 + lm) * 128 + kc * 32 + q * 8);
        #pragma unroll
        for (int j = 0; j < 4; ++j)
            bf[j] = *(const bf16x8*)(Bsl + (wn * 64 + j * 16 + lm) * 128 + kc * 32 + q * 8);
        #pragma unroll
        for (int i = 0; i < 4; ++i)
            #pragma unroll
            for (int j = 0; j < 4; ++j)
                acc[i][j] = __builtin_amdgcn_mfma_f32_16x16x32_bf16(af[i], bf[j], acc[i][j], 0, 0, 0);
    }
    __syncthreads();   // Asl/Bsl/T dead; epi reuses region

    // epilogue: pool adjacent l (reg pairs) + bias + relu -> fp8 -> epi[o][lp]
    #pragma unroll
    for (int j = 0; j < 4; ++j) {
        const int col = wn * 64 + j * 16 + lm;            // o local [0,256)
        const float bias = b1[g * 256 + col];
        #pragma unroll
        for (int i = 0; i < 4; ++i) {
            const float p0 = fmaxf(fmaxf(acc[i][j][0], acc[i][j][1]) + bias, 0.f);
            const float p1 = fmaxf(fmaxf(acc[i][j][2], acc[i][j][3]) + bias, 0.f);
            const int lp_loc = wm * 32 + i * 8 + q * 2;   // [0,64) bytes
            *(unsigned short*)(epi + col * 80 + lp_loc) = f2fp8x2(p0, p1);
        }
    }
    __syncthreads();
    const int c_loc = t >> 1, half = t & 1;
    unsigned char* dst = hb8 + ((size_t)(b * 512 + g * 256 + c_loc)) * 1024 + (l0 >> 1) + half * 32;
    *(int4*)dst        = *(const int4*)(epi + c_loc * 80 + half * 32);
    *(int4*)(dst + 16) = *(const int4*)(epi + c_loc * 80 + half * 32 + 16);
}

// ================ gemm_sc8: Sb[8192,512] bf16 = hb8 . Pb8^T  (MX fp8, K=128/instr)
// 128x64 tile, 256 thr (4 waves, wave-tile 64x32)
__global__ __launch_bounds__(256, 4) void gemm_sc8(
    const unsigned char* __restrict__ A, const unsigned char* __restrict__ B,
    unsigned short* __restrict__ Sb)
{
    const int nt = blockIdx.x & 7;
    const int rt = blockIdx.x >> 3;
    const int r0 = rt * 128, n0 = nt * 64;

    __shared__ unsigned char Asl[128 * 128];  // 16 KB
    __shared__ unsigned char Bsl[64 * 128];   //  8 KB

    const int t = threadIdx.x;
    const int lane = t & 63;
    const int wave = t >> 6;
    const int wm = wave & 1, wn = wave >> 1;
    const int q = lane >> 4, lm = lane & 15;

    f32x4 acc[4][2];
    #pragma unroll
    for (int i = 0; i < 4; ++i)
        #pragma unroll
        for (int j = 0; j < 2; ++j)
            #pragma unroll
            for (int r = 0; r < 4; ++r) acc[i][j][r] = 0.f;

    for (int k0 = 0; k0 < 1024; k0 += 128) {
        #pragma unroll
        for (int rd = 0; rd < 4; ++rd) {   // A: 128x128 B
            const int e = rd * 4096 + t * 16;
            const int row = e >> 7, col = e & 127;
            const unsigned char* ga = A + (size_t)(r0 + row) * 1024 + k0 + col;
            __builtin_amdgcn_global_load_lds((gas_u32*)ga, (las_u32*)(Asl + e), 16, 0, 0);
        }
        #pragma unroll
        for (int rd = 0; rd < 2; ++rd) {   // B: 64x128 B
            const int e = rd * 4096 + t * 16;
            const int row = e >> 7, col = e & 127;
            const unsigned char* gb = B + (size_t)(n0 + row) * 1024 + k0 + col;
            __builtin_amdgcn_global_load_lds((gas_u32*)gb, (las_u32*)(Bsl + e), 16, 0, 0);
        }
        __syncthreads();
        i32x8 af[4], bf[2];
        #pragma unroll
        for (int i = 0; i < 4; ++i)
            af[i] = *(const i32x8*)(Asl + (wm * 64 + i * 16 + lm) * 128 + q * 32);
        #pragma unroll
        for (int j = 0; j < 2; ++j)
            bf[j] = *(const i32x8*)(Bsl + (wn * 32 + j * 16 + lm) * 128 + q * 32);
        #pragma unroll
        for (int i = 0; i < 4; ++i)
            #pragma unroll
            for (int j = 0; j < 2; ++j)
                acc[i][j] = __builtin_amdgcn_mfma_scale_f32_16x16x128_f8f6f4(
                    af[i], bf[j], acc[i][j], 0, 0, 0, SC_UNIT, 0, SC_M6);
        __syncthreads();
    }

    #pragma unroll
    for (int i = 0; i < 4; ++i)
        #pragma unroll
        for (int j = 0; j < 2; ++j)
            #pragma unroll
            for (int r = 0; r < 4; ++r)
                Sb[(size_t)(r0 + wm * 64 + i * 16 + q * 4 + r) * 512
                   + n0 + wn * 32 + j * 16 + lm] = f2bf(acc[i][j][r]);
}

// ================ k_softmax: Sb bf16 -> Ab8 fp8 (x16), rows of 512 (8192 rows)
__global__ __launch_bounds__(256) void k_softmax(
    const unsigned short* __restrict__ Sb, unsigned char* __restrict__ Ab8)
{
    const int row = blockIdx.x * 4 + (threadIdx.x >> 6);
    const int lane = threadIdx.x & 63;
    const u16x8 uv = *(const u16x8*)(Sb + (size_t)row * 512 + lane * 8);

    float v[8];
    #pragma unroll
    for (int j = 0; j < 8; ++j) v[j] = bf2f(uv[j]);

    float mx = v[0];
    #pragma unroll
    for (int j = 1; j < 8; ++j) mx = fmaxf(mx, v[j]);
    for (int off = 32; off > 0; off >>= 1) mx = fmaxf(mx, __shfl_xor(mx, off));

    float sum = 0.f;
    #pragma unroll
    for (int j = 0; j < 8; ++j) { v[j] = __expf(v[j] - mx); sum += v[j]; }
    for (int off = 32; off > 0; off >>= 1) sum += __shfl_xor(sum, off);

    const float inv16 = 16.f / sum;   // store attn*16; retr compensates via MX scale 2^-4
    int2 ov;
    ov.x = f2fp8x4(v[0] * inv16, v[1] * inv16, v[2] * inv16, v[3] * inv16);
    ov.y = f2fp8x4(v[4] * inv16, v[5] * inv16, v[6] * inv16, v[7] * inv16);
    *(int2*)(Ab8 + (size_t)row * 512 + lane * 8) = ov;
}

// ================ gemm_retr8: per-batch h2T[b,lp,c] bf16 = Ptb8 . Ab8^T (MX fp8)
// 128x64 tile, 256 thr
__global__ __launch_bounds__(256, 4) void gemm_retr8(
    const unsigned char* __restrict__ Ptb8, const unsigned char* __restrict__ Ab8,
    unsigned short* __restrict__ h2T)
{
    const int tl = blockIdx.x & 63;
    const int b  = blockIdx.x >> 6;
    const int nt = tl & 7;
    const int rt = tl >> 3;
    const int r0 = rt * 128, n0 = nt * 64;

    __shared__ unsigned char Asl[128 * 128];
    __shared__ unsigned char Bsl[64 * 128];

    const int t = threadIdx.x;
    const int lane = t & 63;
    const int wave = t >> 6;
    const int wm = wave & 1, wn = wave >> 1;
    const int q = lane >> 4, lm = lane & 15;

    f32x4 acc[4][2];
    #pragma unroll
    for (int i = 0; i < 4; ++i)
        #pragma unroll
        for (int j = 0; j < 2; ++j)
            #pragma unroll
            for (int r = 0; r < 4; ++r) acc[i][j][r] = 0.f;

    for (int k0 = 0; k0 < 512; k0 += 128) {
        #pragma unroll
        for (int rd = 0; rd < 4; ++rd) {   // A: 128x128 B of Ptb8
            const int e = rd * 4096 + t * 16;
            const int row = e >> 7, col = e & 127;
            const unsigned char* ga = Ptb8 + (size_t)(r0 + row) * 512 + k0 + col;
            __builtin_amdgcn_global_load_lds((gas_u32*)ga, (las_u32*)(Asl + e), 16, 0, 0);
        }
        #pragma unroll
        for (int rd = 0; rd < 2; ++rd) {   // B: 64x128 B of attn
            const int e = rd * 4096 + t * 16;
            const int row = e >> 7, col = e & 127;
            const unsigned char* gb = Ab8 + ((size_t)b * 512 + n0 + row) * 512 + k0 + col;
            __builtin_amdgcn_global_load_lds((gas_u32*)gb, (las_u32*)(Bsl + e), 16, 0, 0);
        }
        __syncthreads();
        i32x8 af[4], bf[2];
        #pragma unroll
        for (int i = 0; i < 4; ++i)
            af[i] = *(const i32x8*)(Asl + (wm * 64 + i * 16 + lm) * 128 + q * 32);
        #pragma unroll
        for (int j = 0; j < 2; ++j)
            bf[j] = *(const i32x8*)(Bsl + (wn * 32 + j * 16 + lm) * 128 + q * 32);
        #pragma unroll
        for (int i = 0; i < 4; ++i)
            #pragma unroll
            for (int j = 0; j < 2; ++j)
                acc[i][j] = __builtin_amdgcn_mfma_scale_f32_16x16x128_f8f6f4(
                    af[i], bf[j], acc[i][j], 0, 0, 0, SC_M6, 0, SC_M4);
        __syncthreads();
    }

    #pragma unroll
    for (int i = 0; i < 4; ++i)
        #pragma unroll
        for (int j = 0; j < 2; ++j)
            #pragma unroll
            for (int r = 0; r < 4; ++r)
                h2T[((size_t)b * 1024 + r0 + wm * 64 + i * 16 + q * 4 + r) * 512
                    + n0 + wn * 32 + j * 16 + lm] = f2bf(acc[i][j][r]);
}

// ================ k4_gemm: convT via MFMA + fused bias/relu/residual (unchanged)
__global__ __launch_bounds__(256) void k4_gemm(
    const unsigned short* __restrict__ h2T, const unsigned short* __restrict__ wTt,
    const float* __restrict__ bT, const float* __restrict__ x,
    const float* __restrict__ RZ, float* __restrict__ out)
{
    const int nt = blockIdx.x & 1;
    const int g  = (blockIdx.x >> 1) & 1;
    const int rt = blockIdx.x >> 2;
    const int r0 = rt * 128;
    const int b  = r0 >> 10, lp0 = r0 & 1023;

    __shared__ __align__(16) char smem[65536];
    unsigned short* Asl = (unsigned short*)smem;
    unsigned short* Bsl = Asl + 128 * 64;
    float* epi = (float*)smem;

    const int t = threadIdx.x;
    const int lane = t & 63;
    const int wave = t >> 6;
    const int wm = wave & 1, wn = wave >> 1;
    const int q = lane >> 4, lm = lane & 15;

    f32x4 acc[4][4];
    #pragma unroll
    for (int i = 0; i < 4; ++i)
        #pragma unroll
        for (int j = 0; j < 4; ++j)
            #pragma unroll
            for (int r = 0; r < 4; ++r) acc[i][j][r] = 0.f;

    for (int k0 = 0; k0 < 256; k0 += 64) {
        #pragma unroll
        for (int rd = 0; rd < 4; ++rd) {
            const int e = rd * 2048 + t * 8;
            const int row = e >> 6, col = e & 63;
            const unsigned short* ga = h2T + (size_t)(r0 + row) * 512 + g * 256 + k0 + col;
            __builtin_amdgcn_global_load_lds((gas_u32*)ga, (las_u32*)(Asl + e), 16, 0, 0);
            const unsigned short* gb = wTt + (size_t)g * 65536 + (size_t)(nt * 128 + row) * 256 + k0 + col;
            __builtin_amdgcn_global_load_lds((gas_u32*)gb, (las_u32*)(Bsl + e), 16, 0, 0);
        }
        __syncthreads();
        #pragma unroll
        for (int kk = 0; kk < 2; ++kk) {
            bf16x8 af[4], bf[4];
            #pragma unroll
            for (int i = 0; i < 4; ++i)
                af[i] = *(const bf16x8*)(Asl + (wm * 64 + i * 16 + lm) * 64 + kk * 32 + q * 8);
            #pragma unroll
            for (int j = 0; j < 4; ++j)
                bf[j] = *(const bf16x8*)(Bsl + (wn * 64 + j * 16 + lm) * 64 + kk * 32 + q * 8);
            #pragma unroll
            for (int i = 0; i < 4; ++i)
                #pragma unroll
                for (int j = 0; j < 4; ++j)
                    acc[i][j] = __builtin_amdgcn_mfma_f32_16x16x32_bf16(af[i], bf[j], acc[i][j], 0, 0, 0);
        }
        __syncthreads();
    }

    #pragma unroll
    for (int j = 0; j < 4; ++j) {
        const int col_blk = wn * 64 + j * 16 + lm;
        const int o_l = col_blk >> 1, kk2 = col_blk & 1;
        #pragma unroll
        for (int i = 0; i < 4; ++i) {
            #pragma unroll
            for (int r = 0; r < 4; ++r) {
                const int row_l = wm * 64 + i * 16 + q * 4 + r;
                const int l_l = 2 * row_l + kk2;
                const int chunk = ((l_l >> 2) + o_l) & 63;
                epi[o_l * 256 + chunk * 4 + (l_l & 3)] = acc[i][j][r];
            }
        }
    }
    __syncthreads();
    const int row = t >> 2, quad = t & 3;
    const int c = g * 128 + nt * 64 + row;
    const float bias = bT[c];
    const float rz = RZ[0];
    const size_t gbase = ((size_t)(b * 256 + c)) * 2048 + 2 * lp0 + quad * 64;
    #pragma unroll
    for (int k = 0; k < 16; ++k) {
        const int chunk_phys = (quad * 16 + k + row) & 63;
        const float4 v = *(const float4*)(epi + row * 256 + chunk_phys * 4);
        const float4 xv = *(const float4*)(x + gbase + k * 4);
        float4 o;
        o.x = xv.x + rz * fmaxf(v.x + bias, 0.f);
        o.y = xv.y + rz * fmaxf(v.y + bias, 0.f);
        o.z = xv.z + rz * fmaxf(v.z + bias, 0.f);
        o.w = xv.w + rz * fmaxf(v.w + bias, 0.f);
        *(float4*)(out + gbase + k * 4) = o;
    }
}

extern "C" void kernel_launch(void* const* d_in, const int* in_sizes, int n_in,
                              void* d_out, int out_size, void* d_ws, size_t ws_size,
                              hipStream_t stream) {
    (void)in_sizes; (void)n_in; (void)out_size; (void)ws_size;
    const float* x  = (const float*)d_in[0];
    const float* w1 = (const float*)d_in[1];
    const float* b1 = (const float*)d_in[2];
    const float* P  = (const float*)d_in[3];
    const float* wT = (const float*)d_in[4];
    const float* bT = (const float*)d_in[5];
    const float* RZ = (const float*)d_in[6];
    float* out = (float*)d_out;

    // workspace (33.25 MB):
    //   [0,8M)    hb8 fp8 [8192,1024]  (dead after gemm_sc8)
    //   [8,12M)   Ab8 fp8 [8192,512]   (softmax -> retr, x16 pre-scaled)
    //   [16,32M)  h2T bf16 [16,1024,512]
    //   [32M,+512K) Pb8 (x64); [32.5M,+512K) Ptb8 (x64); [33M,+256K) wTt bf16
    // Sb bf16 [8192,512] (8 MB) lives in d_out (dead before k4 overwrites out).
    char* ws = (char*)d_ws;
    unsigned char*  hb8  = (unsigned char*)ws;
    unsigned char*  Ab8  = (unsigned char*)(ws + (8u << 20));
    unsigned short* h2T  = (unsigned short*)(ws + (16u << 20));
    unsigned char*  Pb8  = (unsigned char*)(ws + (32u << 20));
    unsigned char*  Ptb8 = (unsigned char*)(ws + (32u << 20) + (512u << 10));
    unsigned short* wTt  = (unsigned short*)(ws + (33u << 20));
    unsigned short* Sb   = (unsigned short*)out;

    hipLaunchKernelGGL(k_front,    dim3(896),  dim3(512), 0, stream,
                       x, w1, b1, P, wT, hb8, Pb8, Ptb8, wTt);
    hipLaunchKernelGGL(gemm_sc8,   dim3(512),  dim3(256), 0, stream, hb8, Pb8, Sb);
    hipLaunchKernelGGL(k_softmax,  dim3(2048), dim3(256), 0, stream, Sb, Ab8);
    hipLaunchKernelGGL(gemm_retr8, dim3(1024), dim3(256), 0, stream, Ptb8, Ab8, h2T);
    hipLaunchKernelGGL(k4_gemm,    dim3(512),  dim3(256), 0, stream, h2T, wTt, bT, x, RZ, out);
}